// Round 3
// baseline (272.478 us; speedup 1.0000x reference)
//
#include <hip/hip_runtime.h>
#include <cmath>

#define BB 32
#define SS 256
#define HH 768

typedef __attribute__((ext_vector_type(8))) short bfrag8;
typedef __attribute__((ext_vector_type(4))) float accf4;

__device__ __forceinline__ unsigned short f2bf(float x) {   // RTNE fp32->bf16
    unsigned int b = __float_as_uint(x);
    return (unsigned short)((b + 0x7FFFu + ((b >> 16) & 1u)) >> 16);
}

__device__ __forceinline__ float bf2f(unsigned short u) {
    unsigned int b = ((unsigned int)u) << 16;
    return __uint_as_float(b);
}

__device__ __forceinline__ void gload16(const void* g, void* l) {
    __builtin_amdgcn_global_load_lds((const __attribute__((address_space(1))) void*)g,
                                     (__attribute__((address_space(3))) void*)l, 16, 0, 0);
}

// Layouts:
//   qws: [b][kc][srow][32] bf16, LINEAR   (read per-lane direct to VGPR; coalesced 1KB/wave-instr)
//   kws: [b][kc][srow][32] bf16, SWIZZLED (fragment (row,f) at slot f ^ ((row>>1)&3)) —
//        staged via global_load_lds (linear image copy), read via ds_read_b128 conflict-free.

// ---- normcvt: norms + normalized-bf16 packing (pure streaming, no atomics) ----
__global__ __launch_bounds__(256)
void normcvt_kernel(const float* __restrict__ Q, const float* __restrict__ K,
                    unsigned short* __restrict__ qws, unsigned short* __restrict__ kws) {
    const int wave = threadIdx.x >> 6, lane = threadIdx.x & 63;
    const bool isQ = blockIdx.x < 2048;          // rows 0..8191 = Q, else K
    const int rr = (blockIdx.x * 4 + wave) & 8191;
    const float4* src4 = isQ ? (const float4*)(Q + (size_t)rr * HH)
                             : (const float4*)(K + (size_t)rr * HH);
    float4 vv[3]; float s = 0.f;
#pragma unroll
    for (int c = 0; c < 3; ++c) {
        vv[c] = src4[lane + 64 * c];
        s += vv[c].x * vv[c].x + vv[c].y * vv[c].y + vv[c].z * vv[c].z + vv[c].w * vv[c].w;
    }
#pragma unroll
    for (int off = 1; off < 64; off <<= 1) s += __shfl_xor(s, off);
    float inv = 1.f / fmaxf(sqrtf(s), 1e-12f);

    const int b = rr >> 8, srow = rr & 255;
    unsigned short* dst = isQ ? qws : kws;
    const int e = (lane & 7) * 4;                 // true element index of this lane's 4 shorts
    // Q: linear slot; K: swizzled slot
    const int fp8 = isQ ? e
                        : ((((e >> 3) ^ ((srow >> 1) & 3)) << 3) + (e & 7));
#pragma unroll
    for (int c = 0; c < 3; ++c) {
        int kc = (lane >> 3) + 8 * c;
        ushort4 o;
        o.x = f2bf(vv[c].x * inv); o.y = f2bf(vv[c].y * inv);
        o.z = f2bf(vv[c].z * inv); o.w = f2bf(vv[c].w * inv);
        *(ushort4*)(dst + (((size_t)b * 24 + kc) * 256 + srow) * 32 + fp8) = o;
    }
}

// ---- ksum: Ksum[j][h] = sum_t mask(t) * k_norm[j][t][h], from swizzled bf16 planes ----
// grid = 32 j * 24 kc = 768 blocks. tg = tid>>3 (t-stride 32), ec = tid&7 (4-elem chunk).
__global__ __launch_bounds__(256)
void ksum_kernel(const unsigned short* __restrict__ kws, const float* __restrict__ kmask,
                 unsigned short* __restrict__ ksumB) {
    __shared__ float red[4][8][4];   // [wave][ec][4 elems]
    const int j = blockIdx.x / 24, kc = blockIdx.x - j * 24;
    const int lane = threadIdx.x & 63, wv = threadIdx.x >> 6;
    const int tg = threadIdx.x >> 3;              // 0..31
    const int ec = threadIdx.x & 7;               // elem chunk
    const unsigned short* base = kws + ((size_t)(j * 24 + kc)) * 8192;
    const float* km = kmask + j * SS;
    const int f = ec >> 1, off4 = (ec & 1) * 4;   // frag id, offset within frag
    float s0 = 0.f, s1 = 0.f, s2 = 0.f, s3 = 0.f;
    for (int t = tg; t < 256; t += 32) {
        if (km[t] > 0.f) {
            int pos = ((f ^ ((t >> 1) & 3)) << 3) + off4;    // un-swizzle
            ushort4 v = *(const ushort4*)(base + t * 32 + pos);
            s0 += bf2f(v.x); s1 += bf2f(v.y); s2 += bf2f(v.z); s3 += bf2f(v.w);
        }
    }
#pragma unroll
    for (int off = 8; off < 64; off <<= 1) {
        s0 += __shfl_xor(s0, off); s1 += __shfl_xor(s1, off);
        s2 += __shfl_xor(s2, off); s3 += __shfl_xor(s3, off);
    }
    if ((lane >> 3) == 0) {
        red[wv][ec][0] = s0; red[wv][ec][1] = s1; red[wv][ec][2] = s2; red[wv][ec][3] = s3;
    }
    __syncthreads();
    if (threadIdx.x < 32) {
        int e = threadIdx.x;
        float tot = red[0][e >> 2][e & 3] + red[1][e >> 2][e & 3]
                  + red[2][e >> 2][e & 3] + red[3][e >> 2][e & 3];
        ksumB[(size_t)(j * 24 + kc) * 32 + e] = f2bf(tot);
    }
}

// ---- main: banded QK^T + fused base ----
// Q fragments: per-lane direct global->VGPR (no sharing needed).
// K plane: LDS-staged, double-buffered with STATIC buffer names (lk0/lk1, kc-loop
// unrolled x2) so every global_load_lds destination is a compile-time LDS symbol.
// Schedule per kc: STAGE(next) ; COMPUTE(cur) ; one __syncthreads (T3-minimum 2-phase:
// the vmcnt(0) drain at the barrier is covered by the compute phase).
__global__ __launch_bounds__(256, 4)
void mfma_kernel(const unsigned short* __restrict__ qws, const unsigned short* __restrict__ kws,
                 const float* __restrict__ qmask, const float* __restrict__ kmask,
                 const float* __restrict__ araw_p, const float* __restrict__ lscale_p,
                 const unsigned short* __restrict__ ksumB, float* __restrict__ out) {
    __shared__ short lk0[8192];   // K plane buffer A (swizzled image)
    __shared__ short lk1[8192];   // K plane buffer B
    __shared__ short lKsum[768];  // ksumB[j], [kc][32]
    __shared__ float sKm[256];
    __shared__ float wtab[13];
    __shared__ float sRed[4][2];
    __shared__ float sPart[4];
    __shared__ float sKcnt, sQden;

    const int tid = threadIdx.x;
    const int lane = tid & 63, w = tid >> 6;
    const int quad = lane >> 4, col = lane & 15;
    const int i = blockIdx.x >> 5, j = blockIdx.x & 31;

    const float alpha = log1pf(__expf(araw_p[0]));
    const float scale = __expf(lscale_p[0]);

    // ---- phase A ----
    float aq = qmask[i * SS + tid];
    float km = kmask[j * SS + tid];
    sKm[tid] = km;
    float c = (km > 0.f) ? 1.f : 0.f;
#pragma unroll
    for (int off = 1; off < 64; off <<= 1) { aq += __shfl_xor(aq, off); c += __shfl_xor(c, off); }
    if (lane == 0) { sRed[w][0] = aq; sRed[w][1] = c; }
    if (tid < 13) wtab[tid] = __expf(-alpha * (float)tid);
    if (tid < 192) ((ushort4*)lKsum)[tid] = ((const ushort4*)(ksumB + (size_t)j * HH))[tid];

    accf4 acc[4][3];
    accf4 accB[4];
#pragma unroll
    for (int a = 0; a < 4; ++a) {
        accB[a] = (accf4)0.f;
#pragma unroll
        for (int b = 0; b < 3; ++b) acc[a][b] = (accf4)0.f;
    }

    // per-lane Q fragment base (linear layout): row (4w+sbl)*16+col, elems quad*8..
    const unsigned short* qp0 = qws + (size_t)i * 24 * 8192 + (size_t)(4 * w) * 512
                                    + col * 32 + quad * 8;
    // K staging source (swizzled image, linear copy): wave-uniform LDS dest + lane*16B
    const unsigned short* ksrc = kws + (size_t)j * 24 * 8192 + (size_t)w * 2048 + lane * 8;
    const int perm8 = ((quad ^ ((col >> 1) & 3)) << 3);   // swizzled fragment slot (shorts)

#define STAGEK(BUF, KCN) { \
    unsigned short* _d = (unsigned short*)(BUF) + w * 2048; \
    const unsigned short* _s = ksrc + (size_t)(KCN) * 8192; \
    gload16(_s, _d); gload16(_s + 512, _d + 512); \
    gload16(_s + 1024, _d + 1024); gload16(_s + 1536, _d + 1536); }

#define COMPUTE(BUF, KC) { \
    const unsigned short* _qp = qp0 + (size_t)(KC) * 8192; \
    bfrag8 af[4]; \
    af[0] = *(const bfrag8*)(_qp); \
    af[1] = *(const bfrag8*)(_qp + 512); \
    af[2] = *(const bfrag8*)(_qp + 1024); \
    af[3] = *(const bfrag8*)(_qp + 1536); \
    bfrag8 bfr[6]; \
    _Pragma("unroll") \
    for (int u = 0; u < 6; ++u) { \
        int tb = 4 * w - 1 + u; \
        if (tb >= 0 && tb <= 15) \
            bfr[u] = *(const bfrag8*)((const short*)(BUF) + (size_t)(tb * 16 + col) * 32 + perm8); \
    } \
    const bfrag8 kfrag = *(const bfrag8*)(lKsum + (KC) * 32 + quad * 8); \
    _Pragma("unroll") \
    for (int sbl = 0; sbl < 4; ++sbl) { \
        accB[sbl] = __builtin_amdgcn_mfma_f32_16x16x32_bf16(af[sbl], kfrag, accB[sbl], 0, 0, 0); \
        _Pragma("unroll") \
        for (int dtb = 0; dtb < 3; ++dtb) { \
            int tb = 4 * w + sbl - 1 + dtb; \
            if (tb >= 0 && tb <= 15) \
                acc[sbl][dtb] = __builtin_amdgcn_mfma_f32_16x16x32_bf16( \
                    af[sbl], bfr[sbl + dtb], acc[sbl][dtb], 0, 0, 0); \
        } \
    } }

    // prologue: stage kc=0 into lk0 (covered by the same barrier as phase A)
    STAGEK(lk0, 0);
    __syncthreads();
    if (tid == 0) {
        sQden = fmaxf(sRed[0][0] + sRed[1][0] + sRed[2][0] + sRed[3][0], 1.f);
        sKcnt = sRed[0][1] + sRed[1][1] + sRed[2][1] + sRed[3][1];
        // visible to all by the end-of-kc0 barrier; first read is after the loop / kc>=1
    }

    // ---- K loop: 24 chunks of 32, 2-phase pipelined, static double buffer ----
    for (int kc = 0; kc < 24; kc += 2) {
        STAGEK(lk1, kc + 1);
        COMPUTE(lk0, kc);
        __syncthreads();
        if (kc + 2 < 24) STAGEK(lk0, kc + 2);
        COMPUTE(lk1, kc + 1);
        __syncthreads();
    }
#undef STAGEK
#undef COMPUTE

    // ---- epilogue: C/D layout col=lane&15 (t), row=quad*4+reg (s) ----
    const float kcnt = sKcnt;
    float part = 0.f;
#pragma unroll
    for (int sbl = 0; sbl < 4; ++sbl) {
        const int sbase = (4 * w + sbl) * 16 + quad * 4;
        float ns[4] = {0.f, 0.f, 0.f, 0.f}, ds[4] = {0.f, 0.f, 0.f, 0.f};
#pragma unroll
        for (int dtb = 0; dtb < 3; ++dtb) {
            int tb = 4 * w + sbl - 1 + dtb;
            if (tb < 0 || tb > 15) continue;
            int t = tb * 16 + col;
            float kmv = sKm[t];
#pragma unroll
            for (int reg = 0; reg < 4; ++reg) {
                int st = sbase + reg;
                int d = t - st;
                bool ok = (d >= -11) && (d <= 12) && (kmv > 0.f);
                int idx = d < 0 ? -d : d;
                idx = ok ? idx : 0;
                float raw = acc[sbl][dtb][reg];
                float e = ok ? expm1f(scale * raw * wtab[idx]) : 0.f;
                ns[reg] = fmaf(e, raw, ns[reg]);
                ds[reg] += e;
            }
        }
#pragma unroll
        for (int off = 1; off < 16; off <<= 1) {
#pragma unroll
            for (int reg = 0; reg < 4; ++reg) {
                ns[reg] += __shfl_xor(ns[reg], off);
                ds[reg] += __shfl_xor(ds[reg], off);
            }
        }
        if (col == 0) {
#pragma unroll
            for (int reg = 0; reg < 4; ++reg) {
                int st = sbase + reg;
                float qm = qmask[i * SS + st];
                float bse = accB[sbl][reg];      // fused base: all cols equal; col 0 lane has it
                float dtot = ds[reg] + kcnt;
                float v = (qm > 0.f && kcnt > 0.f) ? qm * (ns[reg] + bse) / dtot : 0.f;
                part += v;
            }
        }
    }
    part += __shfl_xor(part, 16);
    part += __shfl_xor(part, 32);
    if (lane == 0) sPart[w] = part;
    __syncthreads();
    if (tid == 0) out[i * BB + j] = (sPart[0] + sPart[1] + sPart[2] + sPart[3]) / sQden;
}

// ============ launcher ============

extern "C" void kernel_launch(void* const* d_in, const int* in_sizes, int n_in,
                              void* d_out, int out_size, void* d_ws, size_t ws_size,
                              hipStream_t stream) {
    const float* Q      = (const float*)d_in[0];
    const float* K      = (const float*)d_in[1];
    const float* qmask  = (const float*)d_in[2];
    const float* kmask  = (const float*)d_in[3];
    const float* araw   = (const float*)d_in[4];
    const float* lscale = (const float*)d_in[5];
    float* outp = (float*)d_out;

    unsigned short* ksumB = (unsigned short*)d_ws;            // 24576 us
    unsigned short* qws = ksumB + 24576;                      // 6291456 us
    unsigned short* kws = qws + 6291456;                      // 6291456 us

    normcvt_kernel<<<4096, 256, 0, stream>>>(Q, K, qws, kws);
    ksum_kernel<<<768, 256, 0, stream>>>(kws, kmask, ksumB);
    mfma_kernel<<<1024, 256, 0, stream>>>(qws, kws, qmask, kmask, araw, lscale, ksumB, outp);
}

// Round 5
// 153.836 us; speedup vs baseline: 1.7712x; 1.7712x over previous
//
#include <hip/hip_runtime.h>
#include <cmath>

#define BB 32
#define SS 256
#define HH 768

typedef __attribute__((ext_vector_type(8))) short bfrag8;
typedef __attribute__((ext_vector_type(4))) float accf4;

__device__ __forceinline__ unsigned short f2bf(float x) {   // RTNE fp32->bf16
    unsigned int b = __float_as_uint(x);
    return (unsigned short)((b + 0x7FFFu + ((b >> 16) & 1u)) >> 16);
}

__device__ __forceinline__ float bf2f(unsigned short u) {
    return __uint_as_float(((unsigned int)u) << 16);
}

__device__ __forceinline__ void gload16(const void* g, void* l) {
    __builtin_amdgcn_global_load_lds((const __attribute__((address_space(1))) void*)g,
                                     (__attribute__((address_space(3))) void*)l, 16, 0, 0);
}

// Layouts (all proven in R2/R3/R0):
//   qws: [b][kc][srow][32] bf16, LINEAR   — read per-lane direct global->VGPR in mfma
//        (wave reads 1KB contiguous per instruction; no cross-wave sharing needed).
//   kws: [b][kc][srow][32] bf16, SWIZZLED (fragment (row,f) at slot f ^ ((row>>1)&3)) —
//        staged via global_load_lds (linear image copy), read via ds_read_b128,
//        0 bank conflicts measured (R0).

// ---- normcvt: norms + normalized-bf16 packing (R3 verbatim; passed) ----
__global__ __launch_bounds__(256)
void normcvt_kernel(const float* __restrict__ Q, const float* __restrict__ K,
                    unsigned short* __restrict__ qws, unsigned short* __restrict__ kws) {
    const int wave = threadIdx.x >> 6, lane = threadIdx.x & 63;
    const bool isQ = blockIdx.x < 2048;          // rows 0..8191 = Q, else K
    const int rr = (blockIdx.x * 4 + wave) & 8191;
    const float4* src4 = isQ ? (const float4*)(Q + (size_t)rr * HH)
                             : (const float4*)(K + (size_t)rr * HH);
    float4 vv[3]; float s = 0.f;
#pragma unroll
    for (int c = 0; c < 3; ++c) {
        vv[c] = src4[lane + 64 * c];
        s += vv[c].x * vv[c].x + vv[c].y * vv[c].y + vv[c].z * vv[c].z + vv[c].w * vv[c].w;
    }
#pragma unroll
    for (int off = 1; off < 64; off <<= 1) s += __shfl_xor(s, off);
    float inv = 1.f / fmaxf(sqrtf(s), 1e-12f);

    const int b = rr >> 8, srow = rr & 255;
    unsigned short* dst = isQ ? qws : kws;
    const int e = (lane & 7) * 4;                 // true element index of this lane's 4 shorts
    // Q: linear slot; K: swizzled slot
    const int fp8 = isQ ? e
                        : ((((e >> 3) ^ ((srow >> 1) & 3)) << 3) + (e & 7));
#pragma unroll
    for (int c = 0; c < 3; ++c) {
        int kc = (lane >> 3) + 8 * c;
        ushort4 o;
        o.x = f2bf(vv[c].x * inv); o.y = f2bf(vv[c].y * inv);
        o.z = f2bf(vv[c].z * inv); o.w = f2bf(vv[c].w * inv);
        *(ushort4*)(dst + (((size_t)b * 24 + kc) * 256 + srow) * 32 + fp8) = o;
    }
}

// ---- ksum: masked K column sums -> ksumB bf16 (R3 verbatim; passed) ----
__global__ __launch_bounds__(256)
void ksum_kernel(const unsigned short* __restrict__ kws, const float* __restrict__ kmask,
                 unsigned short* __restrict__ ksumB) {
    __shared__ float red[4][8][4];   // [wave][ec][4 elems]
    const int j = blockIdx.x / 24, kc = blockIdx.x - j * 24;
    const int lane = threadIdx.x & 63, wv = threadIdx.x >> 6;
    const int tg = threadIdx.x >> 3;              // 0..31
    const int ec = threadIdx.x & 7;               // elem chunk
    const unsigned short* base = kws + ((size_t)(j * 24 + kc)) * 8192;
    const float* km = kmask + j * SS;
    const int f = ec >> 1, off4 = (ec & 1) * 4;   // frag id, offset within frag
    float s0 = 0.f, s1 = 0.f, s2 = 0.f, s3 = 0.f;
    for (int t = tg; t < 256; t += 32) {
        if (km[t] > 0.f) {
            int pos = ((f ^ ((t >> 1) & 3)) << 3) + off4;    // un-swizzle
            ushort4 v = *(const ushort4*)(base + t * 32 + pos);
            s0 += bf2f(v.x); s1 += bf2f(v.y); s2 += bf2f(v.z); s3 += bf2f(v.w);
        }
    }
#pragma unroll
    for (int off = 8; off < 64; off <<= 1) {
        s0 += __shfl_xor(s0, off); s1 += __shfl_xor(s1, off);
        s2 += __shfl_xor(s2, off); s3 += __shfl_xor(s3, off);
    }
    if ((lane >> 3) == 0) {
        red[wv][ec][0] = s0; red[wv][ec][1] = s1; red[wv][ec][2] = s2; red[wv][ec][3] = s3;
    }
    __syncthreads();
    if (threadIdx.x < 32) {
        int e2 = threadIdx.x;
        float tot = red[0][e2 >> 2][e2 & 3] + red[1][e2 >> 2][e2 & 3]
                  + red[2][e2 >> 2][e2 & 3] + red[3][e2 >> 2][e2 & 3];
        ksumB[(size_t)(j * 24 + kc) * 32 + e2] = f2bf(tot);
    }
}

// ---- main: R0 structure, but Q fragments come per-lane DIRECT from global ----
// Per kc: [barrier][stage K only: 4 gload16/wave][barrier+vmcnt drain (half of R0's
// volume)][af direct global loads overlap bfr ds_reads + MFMA stream].
__global__ __launch_bounds__(256, 4)
void mfma_kernel(const unsigned short* __restrict__ qws, const unsigned short* __restrict__ kws,
                 const float* __restrict__ qmask, const float* __restrict__ kmask,
                 const float* __restrict__ araw_p, const float* __restrict__ lscale_p,
                 const unsigned short* __restrict__ ksumB, float* __restrict__ out) {
    __shared__ __align__(16) short lk[8192];   // K plane (swizzled image)
    __shared__ short lKsum[768];               // ksumB[j], [kc][32]
    __shared__ float sKm[256];
    __shared__ float wtab[13];
    __shared__ float sRed[4][2];
    __shared__ float sPart[4];
    __shared__ float sKcnt, sQden;

    const int tid = threadIdx.x;
    const int lane = tid & 63, w = tid >> 6;
    const int quad = lane >> 4, col = lane & 15;
    const int i = blockIdx.x >> 5, j = blockIdx.x & 31;

    const float alpha = log1pf(__expf(araw_p[0]));
    const float scale = __expf(lscale_p[0]);

    // ---- phase A ----
    float aq = qmask[i * SS + tid];
    float km = kmask[j * SS + tid];
    sKm[tid] = km;
    float c = (km > 0.f) ? 1.f : 0.f;
#pragma unroll
    for (int off = 1; off < 64; off <<= 1) { aq += __shfl_xor(aq, off); c += __shfl_xor(c, off); }
    if (lane == 0) { sRed[w][0] = aq; sRed[w][1] = c; }
    if (tid < 13) wtab[tid] = __expf(-alpha * (float)tid);
    if (tid < 192) ((ushort4*)lKsum)[tid] = ((const ushort4*)(ksumB + (size_t)j * HH))[tid];
    __syncthreads();
    if (tid == 0) {
        sQden = fmaxf(sRed[0][0] + sRed[1][0] + sRed[2][0] + sRed[3][0], 1.f);
        sKcnt = sRed[0][1] + sRed[1][1] + sRed[2][1] + sRed[3][1];
    }

    accf4 acc[4][3];
    accf4 accB[4];
#pragma unroll
    for (int a = 0; a < 4; ++a) {
        accB[a] = (accf4)0.f;
#pragma unroll
        for (int b = 0; b < 3; ++b) acc[a][b] = (accf4)0.f;
    }

    // per-lane Q fragment base (linear layout): row (4w+sbl)*16+col, elems quad*8..
    const unsigned short* qp0 = qws + (size_t)i * 24 * 8192 + (size_t)(4 * w) * 512
                                    + col * 32 + quad * 8;
    const size_t kb0 = (size_t)j * 24 * 8192;
    const int perm8 = ((quad ^ ((col >> 1) & 3)) << 3);   // swizzled fragment slot (shorts)

    // ---- K loop: 24 chunks of 32 ----
    for (int kc = 0; kc < 24; ++kc) {
        __syncthreads();
        {
            const unsigned short* ks = kws + kb0 + (size_t)kc * 8192 + w * 2048 + lane * 8;
            unsigned short* lkd = (unsigned short*)lk + w * 2048;   // wave-uniform base
#pragma unroll
            for (int n = 0; n < 4; ++n)
                gload16(ks + n * 512, lkd + n * 512);
        }
        __syncthreads();

        // af direct global loads — issue first so they fly under the ds_reads
        const unsigned short* qp = qp0 + (size_t)kc * 8192;
        bfrag8 af[4];
#pragma unroll
        for (int sbl = 0; sbl < 4; ++sbl)
            af[sbl] = *(const bfrag8*)(qp + sbl * 512);

        const bfrag8 kfrag = *(const bfrag8*)(lKsum + kc * 32 + quad * 8);  // broadcast
        bfrag8 bfr[6];
#pragma unroll
        for (int u = 0; u < 6; ++u) {
            int tb = 4 * w - 1 + u;
            if (tb >= 0 && tb <= 15)
                bfr[u] = *(const bfrag8*)(lk + (size_t)(tb * 16 + col) * 32 + perm8);
        }
#pragma unroll
        for (int sbl = 0; sbl < 4; ++sbl) {
            accB[sbl] = __builtin_amdgcn_mfma_f32_16x16x32_bf16(af[sbl], kfrag, accB[sbl], 0, 0, 0);
#pragma unroll
            for (int dtb = 0; dtb < 3; ++dtb) {
                int tb = 4 * w + sbl - 1 + dtb;
                if (tb >= 0 && tb <= 15)
                    acc[sbl][dtb] = __builtin_amdgcn_mfma_f32_16x16x32_bf16(
                        af[sbl], bfr[sbl + dtb], acc[sbl][dtb], 0, 0, 0);
            }
        }
    }

    // ---- epilogue: C/D layout col=lane&15 (t), row=quad*4+reg (s) ----
    __syncthreads();
    const float kcnt = sKcnt;
    float part = 0.f;
#pragma unroll
    for (int sbl = 0; sbl < 4; ++sbl) {
        const int sbase = (4 * w + sbl) * 16 + quad * 4;
        float ns[4] = {0.f, 0.f, 0.f, 0.f}, ds[4] = {0.f, 0.f, 0.f, 0.f};
#pragma unroll
        for (int dtb = 0; dtb < 3; ++dtb) {
            int tb = 4 * w + sbl - 1 + dtb;
            if (tb < 0 || tb > 15) continue;
            int t = tb * 16 + col;
            float kmv = sKm[t];
#pragma unroll
            for (int reg = 0; reg < 4; ++reg) {
                int st = sbase + reg;
                int d = t - st;
                bool ok = (d >= -11) && (d <= 12) && (kmv > 0.f);
                int idx = d < 0 ? -d : d;
                idx = ok ? idx : 0;
                float raw = acc[sbl][dtb][reg];
                float e = ok ? expm1f(scale * raw * wtab[idx]) : 0.f;
                ns[reg] = fmaf(e, raw, ns[reg]);
                ds[reg] += e;
            }
        }
#pragma unroll
        for (int off = 1; off < 16; off <<= 1) {
#pragma unroll
            for (int reg = 0; reg < 4; ++reg) {
                ns[reg] += __shfl_xor(ns[reg], off);
                ds[reg] += __shfl_xor(ds[reg], off);
            }
        }
        if (col == 0) {
#pragma unroll
            for (int reg = 0; reg < 4; ++reg) {
                int st = sbase + reg;
                float qm = qmask[i * SS + st];
                float bse = accB[sbl][reg];      // fused base: all cols equal; col 0 lane has it
                float dtot = ds[reg] + kcnt;
                float v = (qm > 0.f && kcnt > 0.f) ? qm * (ns[reg] + bse) / dtot : 0.f;
                part += v;
            }
        }
    }
    part += __shfl_xor(part, 16);
    part += __shfl_xor(part, 32);
    if (lane == 0) sPart[w] = part;
    __syncthreads();
    if (tid == 0) out[i * BB + j] = (sPart[0] + sPart[1] + sPart[2] + sPart[3]) / sQden;
}

// ============ launcher ============

extern "C" void kernel_launch(void* const* d_in, const int* in_sizes, int n_in,
                              void* d_out, int out_size, void* d_ws, size_t ws_size,
                              hipStream_t stream) {
    const float* Q      = (const float*)d_in[0];
    const float* K      = (const float*)d_in[1];
    const float* qmask  = (const float*)d_in[2];
    const float* kmask  = (const float*)d_in[3];
    const float* araw   = (const float*)d_in[4];
    const float* lscale = (const float*)d_in[5];
    float* outp = (float*)d_out;

    unsigned short* ksumB = (unsigned short*)d_ws;            // 24576 us
    unsigned short* qws = ksumB + 24576;                      // 6291456 us
    unsigned short* kws = qws + 6291456;                      // 6291456 us

    normcvt_kernel<<<4096, 256, 0, stream>>>(Q, K, qws, kws);
    ksum_kernel<<<768, 256, 0, stream>>>(kws, kmask, ksumB);
    mfma_kernel<<<1024, 256, 0, stream>>>(qws, kws, qmask, kmask, araw, lscale, ksumB, outp);
}

// Round 6
// 152.391 us; speedup vs baseline: 1.7880x; 1.0095x over previous
//
#include <hip/hip_runtime.h>
#include <cmath>

#define BB 32
#define SS 256
#define HH 768

typedef __attribute__((ext_vector_type(8))) short bfrag8;
typedef __attribute__((ext_vector_type(4))) float accf4;

__device__ __forceinline__ unsigned short f2bf(float x) {   // RTNE fp32->bf16
    unsigned int b = __float_as_uint(x);
    return (unsigned short)((b + 0x7FFFu + ((b >> 16) & 1u)) >> 16);
}

__device__ __forceinline__ float bf2f(unsigned short u) {
    return __uint_as_float(((unsigned int)u) << 16);
}

__device__ __forceinline__ void gload16(const void* g, void* l) {
    __builtin_amdgcn_global_load_lds((const __attribute__((address_space(1))) void*)g,
                                     (__attribute__((address_space(3))) void*)l, 16, 0, 0);
}

// Both planes [b][kc][srow][32] bf16, SWIZZLED: fragment (row,f) stored at slot
// f ^ ((row>>1)&3). Staged to LDS as a linear image via global_load_lds; mfma
// ds_read_b128 with perm8 swizzle tiles all 8 bank-groups (0 conflicts, R0).

// ---- normcvt: norms + normalized-bf16 swizzled pack (no atomics; R5 structure) ----
__global__ __launch_bounds__(256)
void normcvt_kernel(const float* __restrict__ Q, const float* __restrict__ K,
                    unsigned short* __restrict__ qws, unsigned short* __restrict__ kws) {
    const int wave = threadIdx.x >> 6, lane = threadIdx.x & 63;
    const bool isQ = blockIdx.x < 2048;          // rows 0..8191 = Q, else K
    const int rr = (blockIdx.x * 4 + wave) & 8191;
    const float4* src4 = isQ ? (const float4*)(Q + (size_t)rr * HH)
                             : (const float4*)(K + (size_t)rr * HH);
    float4 vv[3]; float s = 0.f;
#pragma unroll
    for (int c = 0; c < 3; ++c) {
        vv[c] = src4[lane + 64 * c];
        s += vv[c].x * vv[c].x + vv[c].y * vv[c].y + vv[c].z * vv[c].z + vv[c].w * vv[c].w;
    }
#pragma unroll
    for (int off = 1; off < 64; off <<= 1) s += __shfl_xor(s, off);
    float inv = 1.f / fmaxf(sqrtf(s), 1e-12f);

    const int b = rr >> 8, srow = rr & 255;
    unsigned short* dst = isQ ? qws : kws;
    const int e = (lane & 7) * 4;                 // element index of this lane's 4 shorts
    const int fp8 = (((e >> 3) ^ ((srow >> 1) & 3)) << 3) + (e & 7);   // swizzled slot (both planes)
#pragma unroll
    for (int c = 0; c < 3; ++c) {
        int kc = (lane >> 3) + 8 * c;
        ushort4 o;
        o.x = f2bf(vv[c].x * inv); o.y = f2bf(vv[c].y * inv);
        o.z = f2bf(vv[c].z * inv); o.w = f2bf(vv[c].w * inv);
        *(ushort4*)(dst + (((size_t)b * 24 + kc) * 256 + srow) * 32 + fp8) = o;
    }
}

// ---- ksum: masked K column sums -> ksumB bf16 (R5 verbatim; vectorized) ----
__global__ __launch_bounds__(256)
void ksum_kernel(const unsigned short* __restrict__ kws, const float* __restrict__ kmask,
                 unsigned short* __restrict__ ksumB) {
    __shared__ float red[4][8][4];   // [wave][ec][4 elems]
    const int j = blockIdx.x / 24, kc = blockIdx.x - j * 24;
    const int lane = threadIdx.x & 63, wv = threadIdx.x >> 6;
    const int tg = threadIdx.x >> 3;              // 0..31
    const int ec = threadIdx.x & 7;               // elem chunk
    const unsigned short* base = kws + ((size_t)(j * 24 + kc)) * 8192;
    const float* km = kmask + j * SS;
    const int f = ec >> 1, off4 = (ec & 1) * 4;   // frag id, offset within frag
    float s0 = 0.f, s1 = 0.f, s2 = 0.f, s3 = 0.f;
    for (int t = tg; t < 256; t += 32) {
        if (km[t] > 0.f) {
            int pos = ((f ^ ((t >> 1) & 3)) << 3) + off4;    // un-swizzle
            ushort4 v = *(const ushort4*)(base + t * 32 + pos);
            s0 += bf2f(v.x); s1 += bf2f(v.y); s2 += bf2f(v.z); s3 += bf2f(v.w);
        }
    }
#pragma unroll
    for (int off = 8; off < 64; off <<= 1) {
        s0 += __shfl_xor(s0, off); s1 += __shfl_xor(s1, off);
        s2 += __shfl_xor(s2, off); s3 += __shfl_xor(s3, off);
    }
    if ((lane >> 3) == 0) {
        red[wv][ec][0] = s0; red[wv][ec][1] = s1; red[wv][ec][2] = s2; red[wv][ec][3] = s3;
    }
    __syncthreads();
    if (threadIdx.x < 32) {
        int e2 = threadIdx.x;
        float tot = red[0][e2 >> 2][e2 & 3] + red[1][e2 >> 2][e2 & 3]
                  + red[2][e2 >> 2][e2 & 3] + red[3][e2 >> 2][e2 & 3];
        ksumB[(size_t)(j * 24 + kc) * 32 + e2] = f2bf(tot);
    }
}

// ---- main: banded QK^T + fused base — R0 body VERBATIM (56.4us proven) ----
__global__ __launch_bounds__(256, 4)
void mfma_kernel(const unsigned short* __restrict__ qws, const unsigned short* __restrict__ kws,
                 const float* __restrict__ qmask, const float* __restrict__ kmask,
                 const float* __restrict__ araw_p, const float* __restrict__ lscale_p,
                 const unsigned short* __restrict__ ksumB, float* __restrict__ out) {
    __shared__ __align__(16) short lq[8192];   // one 256x32 bf16 plane (swizzled layout)
    __shared__ __align__(16) short lk[8192];
    __shared__ short lKsum[768]; // ksumB[j], [kc][32]
    __shared__ float sKm[256];
    __shared__ float wtab[13];
    __shared__ float sRed[4][2];
    __shared__ float sPart[4];
    __shared__ float sKcnt, sQden;

    const int tid = threadIdx.x;
    const int lane = tid & 63, w = tid >> 6;
    const int quad = lane >> 4, col = lane & 15;
    const int i = blockIdx.x >> 5, j = blockIdx.x & 31;

    const float alpha = log1pf(__expf(araw_p[0]));
    const float scale = __expf(lscale_p[0]);

    // ---- phase A ----
    float aq = qmask[i * SS + tid];
    float km = kmask[j * SS + tid];
    sKm[tid] = km;
    float c = (km > 0.f) ? 1.f : 0.f;
#pragma unroll
    for (int off = 1; off < 64; off <<= 1) { aq += __shfl_xor(aq, off); c += __shfl_xor(c, off); }
    if (lane == 0) { sRed[w][0] = aq; sRed[w][1] = c; }
    if (tid < 13) wtab[tid] = __expf(-alpha * (float)tid);
    if (tid < 192) ((ushort4*)lKsum)[tid] = ((const ushort4*)(ksumB + (size_t)j * HH))[tid];
    __syncthreads();
    if (tid == 0) {
        sQden = fmaxf(sRed[0][0] + sRed[1][0] + sRed[2][0] + sRed[3][0], 1.f);
        sKcnt = sRed[0][1] + sRed[1][1] + sRed[2][1] + sRed[3][1];
    }

    accf4 acc[4][3];
    accf4 accB[4];
#pragma unroll
    for (int a = 0; a < 4; ++a) {
        accB[a] = (accf4)0.f;
#pragma unroll
        for (int b = 0; b < 3; ++b) acc[a][b] = (accf4)0.f;
    }

    const size_t qb0 = (size_t)i * 24 * 8192;
    const size_t kb0 = (size_t)j * 24 * 8192;
    const int perm8 = ((quad ^ ((col >> 1) & 3)) << 3);   // swizzled fragment slot (shorts)

    // ---- K loop: 24 chunks of 32 ----
    for (int kc = 0; kc < 24; ++kc) {
        __syncthreads();
        {
            const unsigned short* qs = qws + qb0 + (size_t)kc * 8192 + w * 2048 + lane * 8;
            const unsigned short* ks = kws + kb0 + (size_t)kc * 8192 + w * 2048 + lane * 8;
            unsigned short* lqd = (unsigned short*)lq + w * 2048;   // wave-uniform base
            unsigned short* lkd = (unsigned short*)lk + w * 2048;
#pragma unroll
            for (int n = 0; n < 4; ++n) {
                gload16(qs + n * 512, lqd + n * 512);
                gload16(ks + n * 512, lkd + n * 512);
            }
        }
        __syncthreads();

        const bfrag8 kfrag = *(const bfrag8*)(lKsum + kc * 32 + quad * 8);  // broadcast
        bfrag8 bfr[6];
#pragma unroll
        for (int u = 0; u < 6; ++u) {
            int tb = 4 * w - 1 + u;
            if (tb >= 0 && tb <= 15)
                bfr[u] = *(const bfrag8*)(lk + (size_t)(tb * 16 + col) * 32 + perm8);
        }
#pragma unroll
        for (int sbl = 0; sbl < 4; ++sbl) {
            bfrag8 af = *(const bfrag8*)(lq + (size_t)((4 * w + sbl) * 16 + col) * 32 + perm8);
            accB[sbl] = __builtin_amdgcn_mfma_f32_16x16x32_bf16(af, kfrag, accB[sbl], 0, 0, 0);
#pragma unroll
            for (int dtb = 0; dtb < 3; ++dtb) {
                int tb = 4 * w + sbl - 1 + dtb;
                if (tb >= 0 && tb <= 15)
                    acc[sbl][dtb] = __builtin_amdgcn_mfma_f32_16x16x32_bf16(
                        af, bfr[sbl + dtb], acc[sbl][dtb], 0, 0, 0);
            }
        }
    }

    // ---- epilogue: C/D layout col=lane&15 (t), row=quad*4+reg (s) ----
    __syncthreads();
    const float kcnt = sKcnt;
    float part = 0.f;
#pragma unroll
    for (int sbl = 0; sbl < 4; ++sbl) {
        const int sbase = (4 * w + sbl) * 16 + quad * 4;
        float ns[4] = {0.f, 0.f, 0.f, 0.f}, ds[4] = {0.f, 0.f, 0.f, 0.f};
#pragma unroll
        for (int dtb = 0; dtb < 3; ++dtb) {
            int tb = 4 * w + sbl - 1 + dtb;
            if (tb < 0 || tb > 15) continue;
            int t = tb * 16 + col;
            float kmv = sKm[t];
#pragma unroll
            for (int reg = 0; reg < 4; ++reg) {
                int st = sbase + reg;
                int d = t - st;
                bool ok = (d >= -11) && (d <= 12) && (kmv > 0.f);
                int idx = d < 0 ? -d : d;
                idx = ok ? idx : 0;
                float raw = acc[sbl][dtb][reg];
                float e = ok ? expm1f(scale * raw * wtab[idx]) : 0.f;
                ns[reg] = fmaf(e, raw, ns[reg]);
                ds[reg] += e;
            }
        }
#pragma unroll
        for (int off = 1; off < 16; off <<= 1) {
#pragma unroll
            for (int reg = 0; reg < 4; ++reg) {
                ns[reg] += __shfl_xor(ns[reg], off);
                ds[reg] += __shfl_xor(ds[reg], off);
            }
        }
        if (col == 0) {
#pragma unroll
            for (int reg = 0; reg < 4; ++reg) {
                int st = sbase + reg;
                float qm = qmask[i * SS + st];
                float bse = accB[sbl][reg];      // fused base: all cols equal; col 0 lane has it
                float dtot = ds[reg] + kcnt;
                float v = (qm > 0.f && kcnt > 0.f) ? qm * (ns[reg] + bse) / dtot : 0.f;
                part += v;
            }
        }
    }
    part += __shfl_xor(part, 16);
    part += __shfl_xor(part, 32);
    if (lane == 0) sPart[w] = part;
    __syncthreads();
    if (tid == 0) out[i * BB + j] = (sPart[0] + sPart[1] + sPart[2] + sPart[3]) / sQden;
}

// ============ launcher ============

extern "C" void kernel_launch(void* const* d_in, const int* in_sizes, int n_in,
                              void* d_out, int out_size, void* d_ws, size_t ws_size,
                              hipStream_t stream) {
    const float* Q      = (const float*)d_in[0];
    const float* K      = (const float*)d_in[1];
    const float* qmask  = (const float*)d_in[2];
    const float* kmask  = (const float*)d_in[3];
    const float* araw   = (const float*)d_in[4];
    const float* lscale = (const float*)d_in[5];
    float* outp = (float*)d_out;

    unsigned short* ksumB = (unsigned short*)d_ws;            // 24576 us
    unsigned short* qws = ksumB + 24576;                      // 6291456 us
    unsigned short* kws = qws + 6291456;                      // 6291456 us

    normcvt_kernel<<<4096, 256, 0, stream>>>(Q, K, qws, kws);
    ksum_kernel<<<768, 256, 0, stream>>>(kws, kmask, ksumB);
    mfma_kernel<<<1024, 256, 0, stream>>>(qws, kws, qmask, kmask, araw, lscale, ksumB, outp);
}